// Round 17
// baseline (116.248 us; speedup 1.0000x reference)
//
#include <hip/hip_runtime.h>
#include <hip/hip_bf16.h>
#include <stdint.h>

#define B_N 4096
#define V_N 2
#define D_N 1024
#define EPS 1e-8f
#define NTASK 272               // sum_{a=0..31} ceil((a+1)/2); 272 = 8*34
#define NSTEP 16                // K-steps of BK=64 fp8

typedef __attribute__((ext_vector_type(4))) float f32x4;
typedef __attribute__((ext_vector_type(2))) long long ll2;

__device__ __forceinline__ unsigned int f2mono(float f) {
    unsigned int u = __float_as_uint(f);
    return (u & 0x80000000u) ? ~u : (u | 0x80000000u);
}

__device__ __forceinline__ float mono2f(unsigned int m) {
    unsigned int u = (m & 0x80000000u) ? (m ^ 0x80000000u) : ~m;
    return __uint_as_float(u);
}

__device__ __forceinline__ unsigned long long shfl_xor_u64(unsigned long long v, int m) {
    unsigned int lo = (unsigned int)v, hi = (unsigned int)(v >> 32);
    lo = __shfl_xor(lo, m, 64);
    hi = __shfl_xor(hi, m, 64);
    return ((unsigned long long)hi << 32) | lo;
}

// cumulative task count before i-tile a:  S(2m)=m(m+1), S(2m+1)=(m+1)^2
__device__ __forceinline__ int taskcum(int a) {
    int m = a >> 1;
    return (a & 1) ? (m + 1) * (m + 1) : m * (m + 1);
}

#define GLD16(src, dst) __builtin_amdgcn_global_load_lds(                      \
    (const __attribute__((address_space(1))) unsigned int*)(src),             \
    (__attribute__((address_space(3))) unsigned int*)(dst), 16, 0, 0)

// -------- Kernel 1: L2-normalize, emit OCP fp8 e4m3 (V,B,D) ---------------
__global__ __launch_bounds__(256) void knorm(const float* __restrict__ x,
                                             unsigned int* __restrict__ xq) {
    int r = blockIdx.x;            // r = b*V + v  (input rows are contiguous)
    int b = r >> 1, v = r & 1;
    const float* row = x + (size_t)r * D_N;
    int t = threadIdx.x;
    float4 val = reinterpret_cast<const float4*>(row)[t];
    float ss = val.x * val.x + val.y * val.y + val.z * val.z + val.w * val.w;
    #pragma unroll
    for (int s = 32; s > 0; s >>= 1) ss += __shfl_xor(ss, s, 64);
    __shared__ float wsum[4];
    if ((t & 63) == 0) wsum[t >> 6] = ss;
    __syncthreads();
    float tot = wsum[0] + wsum[1] + wsum[2] + wsum[3];
    float rn = 1.0f / sqrtf(tot + EPS);
    int pk = 0;
    pk = __builtin_amdgcn_cvt_pk_fp8_f32(val.x * rn, val.y * rn, pk, false);
    pk = __builtin_amdgcn_cvt_pk_fp8_f32(val.z * rn, val.w * rn, pk, true);
    xq[((size_t)v * B_N + b) * 256 + t] = (unsigned int)pk;
}

// ---- Kernel 2: X·X^T row-argmax, fp8, 128x256 tile, 4 waves, 3 blk/CU -----
// r15-proven minimum-2-phase rhythm. Wave tile 128x64 (wc = wid, wr = 0);
// acc[8][4] (r16-verified epilogue mapping). Ring-2 LDS: A 2x8KB + B 2x16KB
// = 48 KB -> 3 blocks/CU co-resident (the working regime: 256-thr blocks,
// multi-block interleave hides the per-step stall; r16's 1-block/CU failed).
// Steps/CU: 66 -> 34 vs r15. Triangle cover: i-tile a (128 rows) x j-tiles
// b = 0..ceil((a+1)/2)-1 (256 cols); above-diag spill-over entries are
// genuine dots (atomicMax dedups); diag guarded in both epilogues.
__global__ __launch_bounds__(256) void kargmax(const unsigned char* __restrict__ xq,
                                               unsigned long long* __restrict__ rowmax) {
    __shared__ unsigned char lA[2 * 8192];    // 2 bufs x 128 rows x 64 B
    __shared__ unsigned char lB[2 * 16384];   // 2 bufs x 256 rows x 64 B
    const int v = blockIdx.y;
    // T1: chunked XCD swizzle (bijective: 272 = 8*34)
    const int bx = (blockIdx.x & 7) * (NTASK / 8) + (blockIdx.x >> 3);
    int a = (int)(2.0f * sqrtf((float)bx));
    if (a > 31) a = 31;
    while (taskcum(a) > bx) a--;
    while (a < 31 && taskcum(a + 1) <= bx) a++;
    const int b = bx - taskcum(a);
    const int i0 = a * 128;
    const int j0 = b * 256;
    const unsigned char* Xv = xq + (size_t)v * B_N * D_N;

    const int tid = threadIdx.x;
    const int wid = tid >> 6, lane = tid & 63;
    const int wc = wid;                       // 4 N-slices of 64 cols; wr = 0

    f32x4 acc[8][4];
    #pragma unroll
    for (int m = 0; m < 8; m++)
        #pragma unroll
        for (int n = 0; n < 4; n++) acc[m][n] = (f32x4){0.f, 0.f, 0.f, 0.f};

    // Write side: lane l -> row l>>2 of a 16-row chunk, physical 16B slot l&3;
    // source 16B chunk = (l&3) ^ f(row), f(row) = (row>>1)&3 = (l>>3)&3.
    const int csw = ((lane & 3) ^ ((lane >> 3) & 3)) * 16;
    // A: wave covers chunks {wid, wid+4} (rows wid*16 + {0,64} + l>>2)
    const unsigned char* pA = Xv + (size_t)(i0 + wid * 16 + (lane >> 2)) * D_N + csw;
    // B: wave covers chunks {wid, wid+4, wid+8, wid+12}
    const unsigned char* pB = Xv + (size_t)(j0 + wid * 16 + (lane >> 2)) * D_N + csw;

    // Read side: lane group g = lane>>4 reads logical 16B slot g of its row
    // (row%16 = lane&15): physical slot = g ^ f(row)  [PMC 0 conflicts]
    const int fr = ((lane & 15) >> 1) & 3;
    const int rslot = ((lane >> 4) ^ fr) * 16;

#define STAGE(buf, t) do {                                                     \
    const unsigned char* _a = pA + (t) * 64;                                   \
    const unsigned char* _b = pB + (t) * 64;                                   \
    unsigned char* _dA = lA + (buf) * 8192 + wid * 1024;                       \
    unsigned char* _dB = lB + (buf) * 16384 + wid * 1024;                      \
    GLD16(_a,             _dA);                                                \
    GLD16(_a + 64 * D_N,  _dA + 4096);                                         \
    GLD16(_b,             _dB);                                                \
    GLD16(_b + 64 * D_N,  _dB + 4096);                                         \
    GLD16(_b + 128 * D_N, _dB + 8192);                                         \
    GLD16(_b + 192 * D_N, _dB + 12288);                                        \
} while (0)

#define COMPUTE(buf) do {                                                      \
    const unsigned char* _la = lA + (buf) * 8192;                              \
    const unsigned char* _lb = lB + (buf) * 16384;                             \
    ll2 aa[8], bb[4];                                                          \
    _Pragma("unroll")                                                          \
    for (int m = 0; m < 8; m++)                                                \
        aa[m] = *reinterpret_cast<const ll2*>(                                 \
            _la + (m * 16 + (lane & 15)) * 64 + rslot);                        \
    _Pragma("unroll")                                                          \
    for (int n = 0; n < 4; n++)                                                \
        bb[n] = *reinterpret_cast<const ll2*>(                                 \
            _lb + (wc * 64 + n * 16 + (lane & 15)) * 64 + rslot);              \
    __builtin_amdgcn_s_setprio(1);                                             \
    _Pragma("unroll")                                                          \
    for (int m = 0; m < 8; m++)                                                \
        _Pragma("unroll")                                                      \
        for (int n = 0; n < 4; n++) {                                          \
            acc[m][n] = __builtin_amdgcn_mfma_f32_16x16x32_fp8_fp8(            \
                aa[m][0], bb[n][0], acc[m][n], 0, 0, 0);                       \
            acc[m][n] = __builtin_amdgcn_mfma_f32_16x16x32_fp8_fp8(            \
                aa[m][1], bb[n][1], acc[m][n], 0, 0, 0);                       \
        }                                                                      \
    __builtin_amdgcn_s_setprio(0);                                             \
} while (0)

#define STEP_END do {                                                          \
    asm volatile("s_waitcnt vmcnt(0)" ::: "memory");                           \
    __builtin_amdgcn_s_barrier();                                              \
} while (0)

    // ---- Prologue: tile 0 ----
    STAGE(0, 0);
    STEP_END;
    // ---- Main loop (2x unrolled for static buf indices), t = 0..13 ----
    #pragma unroll 1
    for (int t = 0; t < NSTEP - 2; t += 2) {
        STAGE(1, t + 1);        // issue next-tile loads FIRST (T3 order)
        COMPUTE(0);             // tile t
        STEP_END;               // tile t+1 landed; all buf0 reads retired
        STAGE(0, t + 2);
        COMPUTE(1);             // tile t+1
        STEP_END;
    }
    // ---- Tail: t = 14, 15 ----
    STAGE(1, NSTEP - 1);
    COMPUTE(0);                 // tile 14
    STEP_END;
    COMPUTE(1);                 // tile 15

    // ---- Epilogue A: row side (rows i0.., cols j0..) ----
    // C/D layout: col = lane&15, row = (lane>>4)*4 + reg  [m89/m91-verified]
    #pragma unroll
    for (int m = 0; m < 8; m++) {
        int rbase = i0 + m * 16;
        #pragma unroll
        for (int j = 0; j < 4; j++) {
            int grow = rbase + (lane >> 4) * 4 + j;
            unsigned long long best = 0ull;
            #pragma unroll
            for (int n = 0; n < 4; n++) {
                int gcol = j0 + wc * 64 + n * 16 + (lane & 15);
                float vdot = acc[m][n][j];
                unsigned long long p = (grow == gcol)
                    ? 0ull
                    : ((unsigned long long)f2mono(vdot) << 32) | (unsigned int)(~(unsigned int)gcol);
                best = p > best ? p : best;
            }
            #pragma unroll
            for (int s = 1; s < 16; s <<= 1) {
                unsigned long long o = shfl_xor_u64(best, s);
                best = o > best ? o : best;
            }
            if ((lane & 15) == 0)
                atomicMax(&rowmax[(size_t)v * B_N + grow], best);
        }
    }

    // ---- Epilogue B: transposed side (rows j0.., cols i0..) ----
    #pragma unroll
    for (int n = 0; n < 4; n++) {
        int growT = j0 + wc * 64 + n * 16 + (lane & 15);   // C column = transposed row
        unsigned long long best = 0ull;
        #pragma unroll
        for (int m = 0; m < 8; m++) {
            int ibase = i0 + m * 16 + (lane >> 4) * 4;
            #pragma unroll
            for (int j = 0; j < 4; j++) {
                int gi = ibase + j;                        // C row = transposed col
                float vdot = acc[m][n][j];
                unsigned long long p = (gi == growT)
                    ? 0ull
                    : ((unsigned long long)f2mono(vdot) << 32) | (unsigned int)(~(unsigned int)gi);
                best = p > best ? p : best;
            }
        }
        #pragma unroll
        for (int s = 16; s < 64; s <<= 1) {
            unsigned long long o = shfl_xor_u64(best, s);
            best = o > best ? o : best;
        }
        if (lane < 16)
            atomicMax(&rowmax[(size_t)v * B_N + growT], best);
    }
#undef STAGE
#undef COMPUTE
#undef STEP_END
}

// --- Kernel 3: decode loss directly from packed keys, reduce to scalar -----
__global__ __launch_bounds__(1024) void kloss(const unsigned long long* __restrict__ rowmax,
                                              float* __restrict__ out) {
    int t = threadIdx.x;
    float acc = 0.f;
    #pragma unroll
    for (int i = t; i < V_N * B_N; i += 1024) {
        unsigned long long k = rowmax[i];
        float dot = mono2f((unsigned int)(k >> 32));
        float d2 = fmaxf(2.0f - 2.0f * dot, 0.0f);
        acc += -logf(sqrtf(d2) + EPS);
    }
    __shared__ float s[1024];
    s[t] = acc;
    __syncthreads();
    #pragma unroll
    for (int step = 512; step > 0; step >>= 1) {
        if (t < step) s[t] += s[t + step];
        __syncthreads();
    }
    if (t == 0) out[0] = s[0] * (1.0f / (float)B_N);
}

extern "C" void kernel_launch(void* const* d_in, const int* in_sizes, int n_in,
                              void* d_out, int out_size, void* d_ws, size_t ws_size,
                              hipStream_t stream) {
    const float* x = (const float*)d_in[0];
    float* out = (float*)d_out;
    char* ws = (char*)d_ws;

    unsigned int* xq = (unsigned int*)ws;                              // 8 MB fp8
    unsigned long long* rowmax = (unsigned long long*)(ws + 8388608);  // 64 KB

    hipMemsetAsync(rowmax, 0, (size_t)V_N * B_N * sizeof(unsigned long long), stream);
    knorm<<<B_N * V_N, 256, 0, stream>>>(x, xq);
    kargmax<<<dim3(NTASK, V_N), 256, 0, stream>>>((const unsigned char*)xq, rowmax);
    kloss<<<1, 1024, 0, stream>>>(rowmax, out);
}

// Round 18
// 60.169 us; speedup vs baseline: 1.9320x; 1.9320x over previous
//
#include <hip/hip_runtime.h>
#include <hip/hip_bf16.h>
#include <stdint.h>

#define B_N 4096
#define V_N 2
#define D_N 1024
#define EPS 1e-8f
#define NT 32                // 4096/128 tiles per dim
#define NTRI (NT*(NT+1)/2)   // 528 = 8*66 -> clean XCD chunking
#define NSTEP 16             // K-steps of BK=64 fp8

typedef __attribute__((ext_vector_type(4))) float f32x4;
typedef __attribute__((ext_vector_type(2))) long long ll2;

__device__ __forceinline__ unsigned int f2mono(float f) {
    unsigned int u = __float_as_uint(f);
    return (u & 0x80000000u) ? ~u : (u | 0x80000000u);
}

__device__ __forceinline__ float mono2f(unsigned int m) {
    unsigned int u = (m & 0x80000000u) ? (m ^ 0x80000000u) : ~m;
    return __uint_as_float(u);
}

__device__ __forceinline__ unsigned long long shfl_xor_u64(unsigned long long v, int m) {
    unsigned int lo = (unsigned int)v, hi = (unsigned int)(v >> 32);
    lo = __shfl_xor(lo, m, 64);
    hi = __shfl_xor(hi, m, 64);
    return ((unsigned long long)hi << 32) | lo;
}

#define GLD16(src, dst) __builtin_amdgcn_global_load_lds(                      \
    (const __attribute__((address_space(1))) unsigned int*)(src),             \
    (__attribute__((address_space(3))) unsigned int*)(dst), 16, 0, 0)

// -------- Kernel 1: L2-normalize, emit OCP fp8 e4m3 (V,B,D) ---------------
// Also zeroes this block's rowmax slot (replaces the memset dispatch;
// kargmax is stream-ordered after knorm, so this is race-free and
// re-initialized on every call -> replay-safe).
__global__ __launch_bounds__(256) void knorm(const float* __restrict__ x,
                                             unsigned int* __restrict__ xq,
                                             unsigned long long* __restrict__ rowmax) {
    int r = blockIdx.x;            // r = b*V + v  (input rows are contiguous)
    int b = r >> 1, v = r & 1;
    if (threadIdx.x == 0) rowmax[r] = 0ull;
    const float* row = x + (size_t)r * D_N;
    int t = threadIdx.x;
    float4 val = reinterpret_cast<const float4*>(row)[t];
    float ss = val.x * val.x + val.y * val.y + val.z * val.z + val.w * val.w;
    #pragma unroll
    for (int s = 32; s > 0; s >>= 1) ss += __shfl_xor(ss, s, 64);
    __shared__ float wsum[4];
    if ((t & 63) == 0) wsum[t >> 6] = ss;
    __syncthreads();
    float tot = wsum[0] + wsum[1] + wsum[2] + wsum[3];
    float rn = 1.0f / sqrtf(tot + EPS);
    int pk = 0;
    pk = __builtin_amdgcn_cvt_pk_fp8_f32(val.x * rn, val.y * rn, pk, false);
    pk = __builtin_amdgcn_cvt_pk_fp8_f32(val.z * rn, val.w * rn, pk, true);
    xq[((size_t)v * B_N + b) * 256 + t] = (unsigned int)pk;
}

// ------- Kernel 2: per-view X·X^T, row-wise argmax, fp8 MFMA ---------------
// r15-proven config (measured best: 52 us, MfmaUtil 24%, 0 conflicts):
// 128x128 tile, 4 waves (2x2), acc[4][4] (VGPR 64 -> 4-5 blocks/CU -- the
// co-residency that hides the per-step stall; r16/r17 showed bigger wave
// tiles lose more via VGPR-occupancy than they gain), fp8 BK=64, ring-2
// 32 KB LDS, minimum-2-phase rhythm: STAGE(next) -> COMPUTE(cur) ->
// vmcnt(0) -> s_barrier (race-free).  ONE ds_read_b128 per fragment;
// MFMA#1 eats low 8B, MFMA#2 high 8B of each 16B slot. T1 XCD chunking.
__global__ __launch_bounds__(256, 4) void kargmax(const unsigned char* __restrict__ xq,
                                                  unsigned long long* __restrict__ rowmax) {
    __shared__ unsigned char lA[2 * 8192];   // 2 bufs x 128 rows x 64 B
    __shared__ unsigned char lB[2 * 8192];
    const int v = blockIdx.y;
    // T1: chunked XCD swizzle (bijective: 528 = 8*66)
    const int bx = (blockIdx.x & 7) * (NTRI / 8) + (blockIdx.x >> 3);
    int ti = (int)((sqrtf(8.f * (float)bx + 1.f) - 1.f) * 0.5f);
    while ((ti + 1) * (ti + 2) / 2 <= bx) ti++;
    while (ti * (ti + 1) / 2 > bx) ti--;
    const int tj = bx - ti * (ti + 1) / 2;
    const int i0 = ti * 128;
    const int j0 = tj * 128;
    const bool diag = (ti == tj);
    const unsigned char* Xv = xq + (size_t)v * B_N * D_N;

    const int tid = threadIdx.x;
    const int wid = tid >> 6, lane = tid & 63;
    const int wr = wid >> 1, wc = wid & 1;

    f32x4 acc[4][4];
    #pragma unroll
    for (int m = 0; m < 4; m++)
        #pragma unroll
        for (int n = 0; n < 4; n++) acc[m][n] = (f32x4){0.f, 0.f, 0.f, 0.f};

    // Write side: lane l -> row l>>2 of a 16-row chunk, physical 16B slot l&3;
    // source 16B chunk = (l&3) ^ f(row), f(row) = (row>>1)&3 = (l>>3)&3.
    const int csw = ((lane & 3) ^ ((lane >> 3) & 3)) * 16;
    const unsigned char* pA = Xv + (size_t)(i0 + wid * 32 + (lane >> 2)) * D_N + csw;
    const unsigned char* pB = Xv + (size_t)(j0 + wid * 32 + (lane >> 2)) * D_N + csw;

    // Read side: lane group g = lane>>4 reads logical 16B slot g of its row
    // (row%16 = lane&15): physical slot = g ^ f(row)  [PMC 0 conflicts]
    const int fr = ((lane & 15) >> 1) & 3;
    const int rslot = ((lane >> 4) ^ fr) * 16;

#define STAGE(buf, t) do {                                                     \
    const unsigned char* _a = pA + (t) * 64;                                   \
    const unsigned char* _b = pB + (t) * 64;                                   \
    unsigned char* _dA = lA + (buf) * 8192 + wid * 2048;                       \
    unsigned char* _dB = lB + (buf) * 8192 + wid * 2048;                       \
    GLD16(_a,             _dA);                                                \
    GLD16(_a + 16 * D_N,  _dA + 1024);                                         \
    GLD16(_b,             _dB);                                                \
    GLD16(_b + 16 * D_N,  _dB + 1024);                                         \
} while (0)

#define COMPUTE(buf) do {                                                      \
    const unsigned char* _la = lA + (buf) * 8192;                              \
    const unsigned char* _lb = lB + (buf) * 8192;                              \
    ll2 a[4], b[4];                                                            \
    _Pragma("unroll")                                                          \
    for (int m = 0; m < 4; m++)                                                \
        a[m] = *reinterpret_cast<const ll2*>(                                  \
            _la + (wr * 64 + m * 16 + (lane & 15)) * 64 + rslot);              \
    _Pragma("unroll")                                                          \
    for (int n = 0; n < 4; n++)                                                \
        b[n] = *reinterpret_cast<const ll2*>(                                  \
            _lb + (wc * 64 + n * 16 + (lane & 15)) * 64 + rslot);              \
    __builtin_amdgcn_s_setprio(1);                                             \
    _Pragma("unroll")                                                          \
    for (int m = 0; m < 4; m++)                                                \
        _Pragma("unroll")                                                      \
        for (int n = 0; n < 4; n++) {                                          \
            acc[m][n] = __builtin_amdgcn_mfma_f32_16x16x32_fp8_fp8(            \
                a[m][0], b[n][0], acc[m][n], 0, 0, 0);                         \
            acc[m][n] = __builtin_amdgcn_mfma_f32_16x16x32_fp8_fp8(            \
                a[m][1], b[n][1], acc[m][n], 0, 0, 0);                         \
        }                                                                      \
    __builtin_amdgcn_s_setprio(0);                                             \
} while (0)

#define STEP_END do {                                                          \
    asm volatile("s_waitcnt vmcnt(0)" ::: "memory");                           \
    __builtin_amdgcn_s_barrier();                                              \
} while (0)

    // ---- Prologue: tile 0 ----
    STAGE(0, 0);
    STEP_END;
    // ---- Main loop (2x unrolled for static buf indices), t = 0..13 ----
    #pragma unroll 1
    for (int t = 0; t < NSTEP - 2; t += 2) {
        STAGE(1, t + 1);        // issue next-tile loads FIRST (T3 order)
        COMPUTE(0);             // tile t
        STEP_END;               // tile t+1 landed; all buf0 reads retired
        STAGE(0, t + 2);
        COMPUTE(1);             // tile t+1
        STEP_END;
    }
    // ---- Tail: t = 14, 15 ----
    STAGE(1, NSTEP - 1);
    COMPUTE(0);                 // tile 14
    STEP_END;
    COMPUTE(1);                 // tile 15

    // ---- Epilogue A: row side (rows i0.., cols j0..) ----
    // C/D layout: col = lane&15, row = (lane>>4)*4 + reg  [m89/m91-verified]
    #pragma unroll
    for (int m = 0; m < 4; m++) {
        int rbase = i0 + wr * 64 + m * 16;
        #pragma unroll
        for (int j = 0; j < 4; j++) {
            int grow = rbase + (lane >> 4) * 4 + j;
            unsigned long long best = 0ull;
            #pragma unroll
            for (int n = 0; n < 4; n++) {
                int gcol = j0 + wc * 64 + n * 16 + (lane & 15);
                float vdot = acc[m][n][j];
                unsigned long long p = (grow == gcol)
                    ? 0ull
                    : ((unsigned long long)f2mono(vdot) << 32) | (unsigned int)(~(unsigned int)gcol);
                best = p > best ? p : best;
            }
            #pragma unroll
            for (int s = 1; s < 16; s <<= 1) {
                unsigned long long o = shfl_xor_u64(best, s);
                best = o > best ? o : best;
            }
            if ((lane & 15) == 0)
                atomicMax(&rowmax[(size_t)v * B_N + grow], best);
        }
    }

    // ---- Epilogue B: transposed side (rows j0.., cols i0..), off-diag only ----
    if (!diag) {
        #pragma unroll
        for (int n = 0; n < 4; n++) {
            int growT = j0 + wc * 64 + n * 16 + (lane & 15);   // C column = transposed row
            unsigned long long best = 0ull;
            #pragma unroll
            for (int m = 0; m < 4; m++) {
                int ibase = i0 + wr * 64 + m * 16 + (lane >> 4) * 4;
                #pragma unroll
                for (int j = 0; j < 4; j++) {
                    int gi = ibase + j;                        // C row = transposed col
                    float vdot = acc[m][n][j];
                    unsigned long long p =
                        ((unsigned long long)f2mono(vdot) << 32) | (unsigned int)(~(unsigned int)gi);
                    best = p > best ? p : best;
                }
            }
            #pragma unroll
            for (int s = 16; s < 64; s <<= 1) {
                unsigned long long o = shfl_xor_u64(best, s);
                best = o > best ? o : best;
            }
            if (lane < 16)
                atomicMax(&rowmax[(size_t)v * B_N + growT], best);
        }
    }
#undef STAGE
#undef COMPUTE
#undef STEP_END
}

// --- Kernel 3: decode loss directly from packed keys, reduce to scalar -----
// Key = (f2mono(dot) << 32) | ~col ; rows are unit-norm, dist = sqrt(2-2*dot).
// 1024 threads (8 logf/lane), fixed reduction tree -> deterministic.
__global__ __launch_bounds__(1024) void kloss(const unsigned long long* __restrict__ rowmax,
                                              float* __restrict__ out) {
    int t = threadIdx.x;
    float acc = 0.f;
    #pragma unroll
    for (int i = t; i < V_N * B_N; i += 1024) {
        unsigned long long k = rowmax[i];
        float dot = mono2f((unsigned int)(k >> 32));
        float d2 = fmaxf(2.0f - 2.0f * dot, 0.0f);
        acc += -logf(sqrtf(d2) + EPS);
    }
    __shared__ float s[1024];
    s[t] = acc;
    __syncthreads();
    #pragma unroll
    for (int step = 512; step > 0; step >>= 1) {
        if (t < step) s[t] += s[t + step];
        __syncthreads();
    }
    if (t == 0) out[0] = s[0] * (1.0f / (float)B_N);
}

extern "C" void kernel_launch(void* const* d_in, const int* in_sizes, int n_in,
                              void* d_out, int out_size, void* d_ws, size_t ws_size,
                              hipStream_t stream) {
    const float* x = (const float*)d_in[0];
    float* out = (float*)d_out;
    char* ws = (char*)d_ws;

    unsigned int* xq = (unsigned int*)ws;                              // 8 MB fp8
    unsigned long long* rowmax = (unsigned long long*)(ws + 8388608);  // 64 KB

    knorm<<<B_N * V_N, 256, 0, stream>>>(x, xq, rowmax);
    kargmax<<<dim3(NTRI, V_N), 256, 0, stream>>>((const unsigned char*)xq, rowmax);
    kloss<<<1, 1024, 0, stream>>>(rowmax, out);
}

// Round 19
// 55.199 us; speedup vs baseline: 2.1060x; 1.0900x over previous
//
#include <hip/hip_runtime.h>
#include <hip/hip_bf16.h>
#include <stdint.h>

#define B_N 4096
#define V_N 2
#define D_N 1024
#define EPS 1e-8f
#define NT 32                // 4096/128 tiles per dim
#define NTRI (NT*(NT+1)/2)   // 528 = 8*66 -> clean XCD chunking
#define NSTEP 8              // K-steps of BK=128 fp8

typedef __attribute__((ext_vector_type(4))) float f32x4;
typedef __attribute__((ext_vector_type(2))) long long ll2;

__device__ __forceinline__ unsigned int f2mono(float f) {
    unsigned int u = __float_as_uint(f);
    return (u & 0x80000000u) ? ~u : (u | 0x80000000u);
}

__device__ __forceinline__ float mono2f(unsigned int m) {
    unsigned int u = (m & 0x80000000u) ? (m ^ 0x80000000u) : ~m;
    return __uint_as_float(u);
}

__device__ __forceinline__ unsigned long long shfl_xor_u64(unsigned long long v, int m) {
    unsigned int lo = (unsigned int)v, hi = (unsigned int)(v >> 32);
    lo = __shfl_xor(lo, m, 64);
    hi = __shfl_xor(hi, m, 64);
    return ((unsigned long long)hi << 32) | lo;
}

#define GLD16(src, dst) __builtin_amdgcn_global_load_lds(                      \
    (const __attribute__((address_space(1))) unsigned int*)(src),             \
    (__attribute__((address_space(3))) unsigned int*)(dst), 16, 0, 0)

// -------- Kernel 1: L2-normalize, emit OCP fp8 e4m3 (V,B,D) ---------------
// Also zeroes this block's rowmax slot (replaces the memset dispatch).
__global__ __launch_bounds__(256) void knorm(const float* __restrict__ x,
                                             unsigned int* __restrict__ xq,
                                             unsigned long long* __restrict__ rowmax) {
    int r = blockIdx.x;            // r = b*V + v  (input rows are contiguous)
    int b = r >> 1, v = r & 1;
    if (threadIdx.x == 0) rowmax[r] = 0ull;
    const float* row = x + (size_t)r * D_N;
    int t = threadIdx.x;
    float4 val = reinterpret_cast<const float4*>(row)[t];
    float ss = val.x * val.x + val.y * val.y + val.z * val.z + val.w * val.w;
    #pragma unroll
    for (int s = 32; s > 0; s >>= 1) ss += __shfl_xor(ss, s, 64);
    __shared__ float wsum[4];
    if ((t & 63) == 0) wsum[t >> 6] = ss;
    __syncthreads();
    float tot = wsum[0] + wsum[1] + wsum[2] + wsum[3];
    float rn = 1.0f / sqrtf(tot + EPS);
    int pk = 0;
    pk = __builtin_amdgcn_cvt_pk_fp8_f32(val.x * rn, val.y * rn, pk, false);
    pk = __builtin_amdgcn_cvt_pk_fp8_f32(val.z * rn, val.w * rn, pk, true);
    xq[((size_t)v * B_N + b) * 256 + t] = (unsigned int)pk;
}

// ------- Kernel 2: per-view X·X^T, row-wise argmax, fp8 MFMA ---------------
// BK=128 single-buffer variant of the proven structure: per step 8 GLD16 per
// wave in flight (2x r15's MLP -- r8 evidence: more loads/window = higher
// staging BW) and 8 steps (half the stall windows). 128x128 tile, 4 waves,
// acc[4][4] (128 unified regs -> 4 blocks/CU), 32 KB LDS (rows of 128 B).
// Swizzle f(row)=row&7: write source chunk (l&7)^(l>>3) (single formula --
// every GLD16's row-base is a multiple of 8); read physical slot
// (h*4+g)^(row&7), 8 bank-quads x 2 lanes = conflict-free. Two MFMA rounds
// per step (slots {g}, {4+g}); A/B identically permuted -> exact dot.
__global__ __launch_bounds__(256, 4) void kargmax(const unsigned char* __restrict__ xq,
                                                  unsigned long long* __restrict__ rowmax) {
    __shared__ unsigned char lA[16384];   // 128 rows x 128 B
    __shared__ unsigned char lB[16384];
    const int v = blockIdx.y;
    // T1: chunked XCD swizzle (bijective: 528 = 8*66)
    const int bx = (blockIdx.x & 7) * (NTRI / 8) + (blockIdx.x >> 3);
    int ti = (int)((sqrtf(8.f * (float)bx + 1.f) - 1.f) * 0.5f);
    while ((ti + 1) * (ti + 2) / 2 <= bx) ti++;
    while (ti * (ti + 1) / 2 > bx) ti--;
    const int tj = bx - ti * (ti + 1) / 2;
    const int i0 = ti * 128;
    const int j0 = tj * 128;
    const bool diag = (ti == tj);
    const unsigned char* Xv = xq + (size_t)v * B_N * D_N;

    const int tid = threadIdx.x;
    const int wid = tid >> 6, lane = tid & 63;
    const int wr = wid >> 1, wc = wid & 1;

    f32x4 acc[4][4];
    #pragma unroll
    for (int m = 0; m < 4; m++)
        #pragma unroll
        for (int n = 0; n < 4; n++) acc[m][n] = (f32x4){0.f, 0.f, 0.f, 0.f};

    // Write side: GLD16 k covers rows wid*32 + k*8 + (l>>3), physical 16B
    // slot l&7; source chunk = (l&7) ^ f(row), f(row) = row&7 = (l>>3).
    const int csw = ((lane & 7) ^ (lane >> 3)) * 16;
    const unsigned char* pA = Xv + (size_t)(i0 + wid * 32 + (lane >> 3)) * D_N + csw;
    const unsigned char* pB = Xv + (size_t)(j0 + wid * 32 + (lane >> 3)) * D_N + csw;

    // Read side: round h, group g = lane>>4 reads logical slot h*4+g of row
    // (row%16 = lane&15): physical = (h*4+g) ^ (row&7).
    const int rs0 = (((lane >> 4) ^ (lane & 7))) * 16;
    const int rs1 = rs0 ^ 64;

#define STAGE(t) do {                                                          \
    const unsigned char* _a = pA + (t) * 128;                                  \
    const unsigned char* _b = pB + (t) * 128;                                  \
    unsigned char* _dA = lA + wid * 4096;                                      \
    unsigned char* _dB = lB + wid * 4096;                                      \
    GLD16(_a,          _dA);                                                   \
    GLD16(_a +  8192,  _dA + 1024);                                            \
    GLD16(_a + 16384,  _dA + 2048);                                            \
    GLD16(_a + 24576,  _dA + 3072);                                            \
    GLD16(_b,          _dB);                                                   \
    GLD16(_b +  8192,  _dB + 1024);                                            \
    GLD16(_b + 16384,  _dB + 2048);                                            \
    GLD16(_b + 24576,  _dB + 3072);                                            \
} while (0)

#define CROUND(rs) do {                                                        \
    ll2 a[4], b[4];                                                            \
    _Pragma("unroll")                                                          \
    for (int m = 0; m < 4; m++)                                                \
        a[m] = *reinterpret_cast<const ll2*>(                                  \
            lA + (wr * 64 + m * 16 + (lane & 15)) * 128 + (rs));               \
    _Pragma("unroll")                                                          \
    for (int n = 0; n < 4; n++)                                                \
        b[n] = *reinterpret_cast<const ll2*>(                                  \
            lB + (wc * 64 + n * 16 + (lane & 15)) * 128 + (rs));               \
    __builtin_amdgcn_s_setprio(1);                                             \
    _Pragma("unroll")                                                          \
    for (int m = 0; m < 4; m++)                                                \
        _Pragma("unroll")                                                      \
        for (int n = 0; n < 4; n++) {                                          \
            acc[m][n] = __builtin_amdgcn_mfma_f32_16x16x32_fp8_fp8(            \
                a[m][0], b[n][0], acc[m][n], 0, 0, 0);                         \
            acc[m][n] = __builtin_amdgcn_mfma_f32_16x16x32_fp8_fp8(            \
                a[m][1], b[n][1], acc[m][n], 0, 0, 0);                         \
        }                                                                      \
    __builtin_amdgcn_s_setprio(0);                                             \
} while (0)

    // ---- Main loop: 8 steps, single buffer ----
    #pragma unroll 1
    for (int t = 0; t < NSTEP; ++t) {
        STAGE(t);
        asm volatile("s_waitcnt vmcnt(0)" ::: "memory");   // tile t landed
        __builtin_amdgcn_s_barrier();
        CROUND(rs0);           // logical slots g   (K bytes 0..63 of window)
        CROUND(rs1);           // logical slots 4+g (K bytes 64..127)
        __builtin_amdgcn_s_barrier();   // all reads retired before restage
    }

    // ---- Epilogue A: row side (rows i0.., cols j0..) ----
    // C/D layout: col = lane&15, row = (lane>>4)*4 + reg  [m89/m91-verified]
    #pragma unroll
    for (int m = 0; m < 4; m++) {
        int rbase = i0 + wr * 64 + m * 16;
        #pragma unroll
        for (int j = 0; j < 4; j++) {
            int grow = rbase + (lane >> 4) * 4 + j;
            unsigned long long best = 0ull;
            #pragma unroll
            for (int n = 0; n < 4; n++) {
                int gcol = j0 + wc * 64 + n * 16 + (lane & 15);
                float vdot = acc[m][n][j];
                unsigned long long p = (grow == gcol)
                    ? 0ull
                    : ((unsigned long long)f2mono(vdot) << 32) | (unsigned int)(~(unsigned int)gcol);
                best = p > best ? p : best;
            }
            #pragma unroll
            for (int s = 1; s < 16; s <<= 1) {
                unsigned long long o = shfl_xor_u64(best, s);
                best = o > best ? o : best;
            }
            if ((lane & 15) == 0)
                atomicMax(&rowmax[(size_t)v * B_N + grow], best);
        }
    }

    // ---- Epilogue B: transposed side (rows j0.., cols i0..), off-diag only ----
    if (!diag) {
        #pragma unroll
        for (int n = 0; n < 4; n++) {
            int growT = j0 + wc * 64 + n * 16 + (lane & 15);   // C column = transposed row
            unsigned long long best = 0ull;
            #pragma unroll
            for (int m = 0; m < 4; m++) {
                int ibase = i0 + wr * 64 + m * 16 + (lane >> 4) * 4;
                #pragma unroll
                for (int j = 0; j < 4; j++) {
                    int gi = ibase + j;                        // C row = transposed col
                    float vdot = acc[m][n][j];
                    unsigned long long p =
                        ((unsigned long long)f2mono(vdot) << 32) | (unsigned int)(~(unsigned int)gi);
                    best = p > best ? p : best;
                }
            }
            #pragma unroll
            for (int s = 16; s < 64; s <<= 1) {
                unsigned long long o = shfl_xor_u64(best, s);
                best = o > best ? o : best;
            }
            if (lane < 16)
                atomicMax(&rowmax[(size_t)v * B_N + growT], best);
        }
    }
#undef STAGE
#undef CROUND
}

// --- Kernel 3: decode loss directly from packed keys, reduce to scalar -----
// Key = (f2mono(dot) << 32) | ~col ; rows are unit-norm, dist = sqrt(2-2*dot).
__global__ __launch_bounds__(1024) void kloss(const unsigned long long* __restrict__ rowmax,
                                              float* __restrict__ out) {
    int t = threadIdx.x;
    float acc = 0.f;
    #pragma unroll
    for (int i = t; i < V_N * B_N; i += 1024) {
        unsigned long long k = rowmax[i];
        float dot = mono2f((unsigned int)(k >> 32));
        float d2 = fmaxf(2.0f - 2.0f * dot, 0.0f);
        acc += -logf(sqrtf(d2) + EPS);
    }
    __shared__ float s[1024];
    s[t] = acc;
    __syncthreads();
    #pragma unroll
    for (int step = 512; step > 0; step >>= 1) {
        if (t < step) s[t] += s[t + step];
        __syncthreads();
    }
    if (t == 0) out[0] = s[0] * (1.0f / (float)B_N);
}

extern "C" void kernel_launch(void* const* d_in, const int* in_sizes, int n_in,
                              void* d_out, int out_size, void* d_ws, size_t ws_size,
                              hipStream_t stream) {
    const float* x = (const float*)d_in[0];
    float* out = (float*)d_out;
    char* ws = (char*)d_ws;

    unsigned int* xq = (unsigned int*)ws;                              // 8 MB fp8
    unsigned long long* rowmax = (unsigned long long*)(ws + 8388608);  // 64 KB

    knorm<<<B_N * V_N, 256, 0, stream>>>(x, xq, rowmax);
    kargmax<<<dim3(NTRI, V_N), 256, 0, stream>>>((const unsigned char*)xq, rowmax);
    kloss<<<1, 1024, 0, stream>>>(rowmax, out);
}